// Round 3
// baseline (491.679 us; speedup 1.0000x reference)
//
#include <hip/hip_runtime.h>
#include <math.h>

#define DIM 768
#define HWS 56
#define PLANE (HWS * HWS)     // 3136
#define PLANE4 (PLANE / 4)    // 784
#define LSTRIDE 64
#define LROWS 59              // 1 underflow row + 1 top halo + 56 data + 1 bottom halo

__device__ __forceinline__ float quant_fixed(float x) {
    // floor(x/2^-16 + 0.5) * 2^-16, clipped to [-2^15, 2^15 - 1] — fp32-exact
    float t = x * 65536.0f;
    t = t + 0.5f;
    t = floorf(t);
    float r = t * (1.0f / 65536.0f);
    r = fmaxf(r, -32768.0f);
    r = fminf(r, 32767.0f);
    return r;
}

__global__ __launch_bounds__(256, 8) void peg_shift_dwconv(
        const float* __restrict__ x, const float* __restrict__ weight,
        const float* __restrict__ bias, float* __restrict__ out) {
    // Padded LDS tile: data row h lives at flat row (h+2); rows 0,1,58 are zero,
    // cols 56..63 of data rows are zero. A read at (row r, col -1) lands on
    // (row r-1, col 63) which is always zero -> branchless 3x3 stencil.
    __shared__ __align__(16) float tile[LROWS * LSTRIDE];
    __shared__ float qw_s[9];
    __shared__ float bias_s;

    const int tid = threadIdx.x;
    const int plane = blockIdx.x;          // n*768 + c
    const int c = plane % DIM;

    // --- zero halo: full rows 0, 1, 58 (192 floats) ---
    if (tid < 192) {
        int r = tid >> 6;
        int row = (r == 2) ? 58 : r;
        tile[row * LSTRIDE + (tid & 63)] = 0.0f;
    }
    // --- zero cols 56..63 of rows 2..57 (448 floats) ---
    for (int i = tid; i < 448; i += 256) {
        int row = 2 + (i >> 3);
        int col = 56 + (i & 7);
        tile[row * LSTRIDE + col] = 0.0f;
    }
    // --- quantize the 9 weights of this channel (round-half-even like jnp.round) ---
    if (tid < 9) {
        float wv = weight[c * 9 + tid];
        float a = fabsf(wv) + 1e-32f;
        float sh = rintf(log2f(a));
        sh = fminf(fmaxf(sh, -14.0f), 0.0f);
        float p = exp2f(sh);
        float s = (wv > 0.0f) ? 1.0f : ((wv < 0.0f) ? -1.0f : 0.0f);
        qw_s[tid] = s * p;
    }
    if (tid == 9) bias_s = bias[c];

    // --- stage + quantize the 56x56 plane (784 float4 loads, 16B-aligned) ---
    const float4* in4 = (const float4*)(x + (size_t)plane * PLANE);
    for (int j = tid; j < PLANE4; j += 256) {
        float4 v = in4[j];
        v.x = quant_fixed(v.x);
        v.y = quant_fixed(v.y);
        v.z = quant_fixed(v.z);
        v.w = quant_fixed(v.w);
        int h = j / 14;           // row of this float4
        int q = j - h * 14;       // float4 index within row
        *(float4*)&tile[(h + 2) * LSTRIDE + q * 4] = v;
    }
    __syncthreads();

    float k[9];
    #pragma unroll
    for (int i = 0; i < 9; ++i) k[i] = qw_s[i];
    const float bv = bias_s;

    // --- compute: column strip per thread, 3-row rolling registers ---
    const int w = tid & 63;
    const int strip = tid >> 6;            // 0..3 -> rows strip*14 .. +13
    const bool is_active = (w < HWS);
    const int wc = is_active ? w : 0;      // keep inactive lanes in-bounds
    const int h0 = strip * 14;
    float* outp = out + (size_t)plane * PLANE;

    // rows h0-1 (flat h0+1) and h0 (flat h0+2)
    int ra = (h0 + 1) * LSTRIDE + wc;
    int rb = (h0 + 2) * LSTRIDE + wc;
    float a0 = tile[ra - 1], a1 = tile[ra], a2 = tile[ra + 1];
    float b0 = tile[rb - 1], b1 = tile[rb], b2 = tile[rb + 1];

    #pragma unroll
    for (int h = h0; h < h0 + 14; ++h) {
        int rc = (h + 3) * LSTRIDE + wc;   // data row h+1
        float c0 = tile[rc - 1], c1 = tile[rc], c2 = tile[rc + 1];
        float acc = bv;
        acc += k[0] * a0; acc += k[1] * a1; acc += k[2] * a2;
        acc += k[3] * b0; acc += k[4] * b1; acc += k[5] * b2;
        acc += k[6] * c0; acc += k[7] * c1; acc += k[8] * c2;
        if (is_active) outp[h * HWS + w] = acc;
        a0 = b0; a1 = b1; a2 = b2;
        b0 = c0; b1 = c1; b2 = c2;
    }
}

extern "C" void kernel_launch(void* const* d_in, const int* in_sizes, int n_in,
                              void* d_out, int out_size, void* d_ws, size_t ws_size,
                              hipStream_t stream) {
    const float* x = (const float*)d_in[0];
    const float* wgt = (const float*)d_in[1];
    const float* bias = (const float*)d_in[2];
    float* out = (float*)d_out;
    const int nplanes = in_sizes[0] / PLANE;   // 32*768 = 24576
    peg_shift_dwconv<<<nplanes, 256, 0, stream>>>(x, wgt, bias, out);
}